// Round 12
// baseline (137.169 us; speedup 1.0000x reference)
//
#include <hip/hip_runtime.h>
#include <math.h>

#define THREADS 1024   // 16 waves/block, 1 block/CU at grid 256 (best measured geometry)
#define NBLOCKS 256
#define UNROLL  8      // k_loss MLP batch
#define SUNROLL 16     // k_stats MLP batch (single round: 32 outstanding loads/thread)

typedef __attribute__((ext_vector_type(2))) float f2v;

// ---- monotone float <-> uint encoding (order-preserving) ----
__device__ __forceinline__ unsigned enc_f(float f) {
    unsigned b = __float_as_uint(f);
    return (b & 0x80000000u) ? ~b : (b | 0x80000000u);
}
__device__ __forceinline__ float dec_f(unsigned u) {
    unsigned b = (u & 0x80000000u) ? (u ^ 0x80000000u) : ~u;
    return __uint_as_float(b);
}
#define ENC_NEG_INF 0x007FFFFFu   // enc(-inf): identity for max
#define ENC_POS_INF 0xFF800000u   // enc(+inf): identity for min
// stat word w: [0..7] gmax(max) [8..15] pmin(min) [16..23] zmin(min) [24..31] zmax(max)
__device__ __forceinline__ unsigned ident_w(int w) {
    return (w < 8 || w >= 24) ? ENC_NEG_INF : ENC_POS_INF;
}

// ws (unsigned*): [32..33] double acc | [34] done-counter (zeroed by k_stats blk 0)
//                 [64 + blk*32 + w] per-block stat slots
#define SLOT(base, blk) ((base) + 64 + (blk) * 32)

#define CNT_B(ii, bdst) do { bdst = 0; \
    _Pragma("unroll") for (int j_ = 0; j_ < 8; ++j_) bdst += ((ii) >= roff[j_]); } while (0)

#define FLUSH_LDS(bb, g_, p_, mn_, mx_) do { \
    atomicMax(&s_stats[      (bb)], enc_f(g_));  \
    atomicMin(&s_stats[ 8  + (bb)], enc_f(p_));  \
    atomicMin(&s_stats[16  + (bb)], enc_f(mn_)); \
    atomicMax(&s_stats[24  + (bb)], enc_f(mx_)); } while (0)

__global__ __launch_bounds__(THREADS) void k_stats(
        const float* __restrict__ coord, const int* __restrict__ segment,
        const int* __restrict__ offset, unsigned* __restrict__ ws, int n, int nb) {
    __shared__ unsigned s_stats[32];
    const int tid = threadIdx.x;
    if (tid < 32) s_stats[tid] = ident_w(tid);
    if (blockIdx.x == 0 && tid == THREADS - 1) {   // zero acc + done (no k_init kernel)
        *(double*)(ws + 32) = 0.0;
        ws[34] = 0u;
    }
    int roff[8];
    #pragma unroll
    for (int j = 0; j < 8; ++j) roff[j] = (j < nb) ? offset[j] : 0x7FFFFFFF;
    __syncthreads();

    const int chunk = (n + (int)gridDim.x - 1) / (int)gridDim.x;
    const int start = blockIdx.x * chunk;
    const int end   = min(n, start + chunk);

    float lg = -INFINITY, lp = INFINITY, lmn = INFINITY, lmx = -INFINITY;

    if (start < end) {
        int ba = 0, bb = 0;
        #pragma unroll
        for (int j = 0; j < 8; ++j) { ba += (start >= roff[j]); bb += ((end - 1) >= roff[j]); }
        if (ba == bb) {
            // ---- fast path: one cloud; nontemporal scalar coalesced loads, 16x MLP ----
            int i = start + tid;
            for (; i + (SUNROLL - 1) * THREADS < end; i += SUNROLL * THREADS) {
                float z[SUNROLL]; int s[SUNROLL];
                #pragma unroll
                for (int k = 0; k < SUNROLL; ++k)
                    z[k] = __builtin_nontemporal_load(&coord[3 * (i + k * THREADS) + 2]);
                #pragma unroll
                for (int k = 0; k < SUNROLL; ++k)
                    s[k] = __builtin_nontemporal_load(&segment[i + k * THREADS]);
                #pragma unroll
                for (int k = 0; k < SUNROLL; ++k) {
                    lmn = fminf(lmn, z[k]);
                    lmx = fmaxf(lmx, z[k]);
                    lg  = fmaxf(lg, (s[k] == 0) ? z[k] : -INFINITY);
                    lp  = fminf(lp, (s[k] != 0) ? z[k] : INFINITY);
                }
            }
            for (; i < end; i += THREADS) {
                float z = coord[3 * i + 2]; int s = segment[i];
                lmn = fminf(lmn, z); lmx = fmaxf(lmx, z);
                lg  = fmaxf(lg, (s == 0) ? z : -INFINITY);
                lp  = fminf(lp, (s != 0) ? z : INFINITY);
            }
            #pragma unroll
            for (int m = 32; m; m >>= 1) {
                lg  = fmaxf(lg,  __shfl_xor(lg,  m, 64));
                lp  = fminf(lp,  __shfl_xor(lp,  m, 64));
                lmn = fminf(lmn, __shfl_xor(lmn, m, 64));
                lmx = fmaxf(lmx, __shfl_xor(lmx, m, 64));
            }
            if ((tid & 63) == 0) FLUSH_LDS(ba, lg, lp, lmn, lmx);
        } else {
            // ---- slow path (<= B-1 boundary blocks): per-point batch tracking ----
            int curb = -1;
            for (int i = start + tid; i < end; i += THREADS) {
                float z = coord[3 * i + 2]; int s = segment[i], b;
                CNT_B(i, b);
                if (b != curb) {
                    if (curb >= 0) FLUSH_LDS(curb, lg, lp, lmn, lmx);
                    lg = -INFINITY; lp = INFINITY; lmn = INFINITY; lmx = -INFINITY;
                    curb = b;
                }
                lmn = fminf(lmn, z); lmx = fmaxf(lmx, z);
                if (s == 0) lg = fmaxf(lg, z); else lp = fminf(lp, z);
            }
            if (curb >= 0) FLUSH_LDS(curb, lg, lp, lmn, lmx);
        }
    }
    __syncthreads();
    if (tid < 32) SLOT(ws, blockIdx.x)[tid] = s_stats[tid];   // plain-store publish
}

// C=2 softmax == sigmoid of the logit margin (algebraically identical, fewer trans ops):
//   delta = x_t - x_other; u = exp(-delta); pt = 1/(1+u); om = 1-pt = u/(1+u);
//   lpt = -log(1+u); loss = -lpt*om^2 = log(1+u)*om^2
__device__ __forceinline__ float point_loss(float p0, float p1, int s, float z, float mu) {
    float dlt = (s == 0) ? (p0 - p1) : (p1 - p0);
    float u   = expf(fminf(-dlt, 80.0f));          // clamp: e^80 finite, asymptote exact
    float inv = __builtin_amdgcn_rcpf(1.0f + u);   // v_rcp: ~1e-5 rel, far under threshold
    float om  = u * inv;                           // 1 - pt
    float l1u = logf(1.0f + u);                    // -lpt
    float loss = l1u * om * om;                    // LOSS_WEIGHT=ALPHA=1, GAMMA=2
    float d  = z - mu;
    float cf = (z <= mu) ? 50.0f : 3.125f;         // 1/(2*0.1^2), 1/(2*0.4^2)
    float w  = expf(-d * d * cf);
    if (d > 0.8f) w = 0.1f;                        // d>0.8 implies z>mu
    return loss * w;
}

__global__ __launch_bounds__(THREADS) void k_loss(
        const float* __restrict__ pred, const float* __restrict__ coord,
        const int* __restrict__ segment, const int* __restrict__ offset,
        unsigned* __restrict__ ws, float* __restrict__ out, int n, int nb) {
    __shared__ unsigned s_comb[32];
    __shared__ float    s_mu[8];
    __shared__ float    s_part[THREADS / 64];
    const int tid = threadIdx.x;
    int roff[8];
    #pragma unroll
    for (int j = 0; j < 8; ++j) roff[j] = (j < nb) ? offset[j] : 0x7FFFFFFF;

    // ---- reduce the 256 per-block stat records ----
    if (tid < 32) s_comb[tid] = ident_w(tid);
    __syncthreads();
    {
        const int w = tid & 31, g = tid >> 5;
        unsigned v = ident_w(w);
        #pragma unroll
        for (int j = 0; j < NBLOCKS / 32; ++j) {
            unsigned u = SLOT((const unsigned*)ws, g * (NBLOCKS / 32) + j)[w];
            v = (w < 8 || w >= 24) ? max(v, u) : min(v, u);
        }
        if (w < 8 || w >= 24) atomicMax(&s_comb[w], v);
        else                  atomicMin(&s_comb[w], v);
    }
    __syncthreads();
    if (tid < 8) {
        unsigned ug = s_comb[tid], up = s_comb[8 + tid];
        float g = dec_f(ug), p = dec_f(up);
        if (ug == ENC_NEG_INF) g = dec_f(s_comb[16 + tid]);  // no ground -> z.min
        if (up == ENC_POS_INF) p = dec_f(s_comb[24 + tid]);  // no plant  -> z.max
        s_mu[tid] = g + (p - g) * 0.5f;
    }
    __syncthreads();

    const int chunk = (n + (int)gridDim.x - 1) / (int)gridDim.x;
    const int start = blockIdx.x * chunk;
    const int end   = min(n, start + chunk);
    const f2v* pred2 = (const f2v*)pred;

    float lsum = 0.0f;
    if (start < end) {
        int ba = 0, bb = 0;
        #pragma unroll
        for (int j = 0; j < 8; ++j) { ba += (start >= roff[j]); bb += ((end - 1) >= roff[j]); }
        if (ba == bb) {
            const float mu = s_mu[ba];       // hoisted, no LDS in hot loop
            int i = start + tid;
            for (; i + (UNROLL - 1) * THREADS < end; i += UNROLL * THREADS) {
                float z[UNROLL]; int s[UNROLL]; f2v pp[UNROLL];
                #pragma unroll
                for (int k = 0; k < UNROLL; ++k)
                    pp[k] = __builtin_nontemporal_load(&pred2[i + k * THREADS]);
                #pragma unroll
                for (int k = 0; k < UNROLL; ++k)
                    z[k] = __builtin_nontemporal_load(&coord[3 * (i + k * THREADS) + 2]);
                #pragma unroll
                for (int k = 0; k < UNROLL; ++k)
                    s[k] = __builtin_nontemporal_load(&segment[i + k * THREADS]);
                #pragma unroll
                for (int k = 0; k < UNROLL; ++k)
                    lsum += point_loss(pp[k].x, pp[k].y, s[k], z[k], mu);
            }
            for (; i < end; i += THREADS) {
                f2v pp = pred2[i];
                lsum += point_loss(pp.x, pp.y, segment[i], coord[3 * i + 2], mu);
            }
        } else {
            for (int i = start + tid; i < end; i += THREADS) {
                int b; CNT_B(i, b);
                f2v pp = pred2[i];
                lsum += point_loss(pp.x, pp.y, segment[i], coord[3 * i + 2], s_mu[b]);
            }
        }
    }

    #pragma unroll
    for (int off = 32; off > 0; off >>= 1) lsum += __shfl_down(lsum, off, 64);
    if ((tid & 63) == 0) s_part[tid >> 6] = lsum;
    __syncthreads();
    if (tid == 0) {
        float t = 0.0f;
        #pragma unroll
        for (int wv = 0; wv < THREADS / 64; ++wv) t += s_part[wv];
        double* acc = (double*)(ws + 32);
        atomicAdd(acc, (double)t);
        __threadfence();
        unsigned c = atomicAdd(&ws[34], 1u);
        if (c == (unsigned)gridDim.x - 1u) {       // last block finalizes
            double v = atomicAdd(acc, 0.0);        // coherent read via atomic
            out[0] = (float)(v / (double)n);
        }
    }
}

extern "C" void kernel_launch(void* const* d_in, const int* in_sizes, int n_in,
                              void* d_out, int out_size, void* d_ws, size_t ws_size,
                              hipStream_t stream) {
    const float* pred    = (const float*)d_in[0];
    const float* coord   = (const float*)d_in[1];
    const int*   segment = (const int*)d_in[2];
    const int*   offset  = (const int*)d_in[3];
    const int n  = in_sizes[2];
    const int nb = in_sizes[3];

    unsigned* ws = (unsigned*)d_ws;

    hipLaunchKernelGGL(k_stats, dim3(NBLOCKS), dim3(THREADS), 0, stream,
                       coord, segment, offset, ws, n, nb);
    hipLaunchKernelGGL(k_loss,  dim3(NBLOCKS), dim3(THREADS), 0, stream,
                       pred, coord, segment, offset, ws, (float*)d_out, n, nb);
}

// Round 13
// 132.618 us; speedup vs baseline: 1.0343x; 1.0343x over previous
//
#include <hip/hip_runtime.h>
#include <math.h>

#define THREADS 1024   // 16 waves/block, 1 block/CU at grid 256 (R8-best geometry)
#define NBLOCKS 256
#define UNROLL  8

// ---- monotone float <-> uint encoding (order-preserving) ----
__device__ __forceinline__ unsigned enc_f(float f) {
    unsigned b = __float_as_uint(f);
    return (b & 0x80000000u) ? ~b : (b | 0x80000000u);
}
__device__ __forceinline__ float dec_f(unsigned u) {
    unsigned b = (u & 0x80000000u) ? (u ^ 0x80000000u) : ~u;
    return __uint_as_float(b);
}
#define ENC_NEG_INF 0x007FFFFFu   // enc(-inf): identity for max
#define ENC_POS_INF 0xFF800000u   // enc(+inf): identity for min
// word w in a 32-word stat record: [0..7] gmax(max) [8..15] pmin(min) [16..23] zmin(min) [24..31] zmax(max)
__device__ __forceinline__ unsigned ident_w(int w) {
    return (w < 8 || w >= 24) ? ENC_NEG_INF : ENC_POS_INF;
}

// ws layout (unsigned*):
//   [32..33] double acc  | [34] done-counter        (zeroed by k_stats block 0)
//   [64 + blk*32 + w]    per-block stat slots        (written by every k_stats block)
#define SLOT(base, blk) ((base) + 64 + (blk) * 32)

#define CNT_B(ii, bdst) do { bdst = 0; \
    _Pragma("unroll") for (int j_ = 0; j_ < 8; ++j_) bdst += ((ii) >= roff[j_]); } while (0)

#define FLUSH_LDS(bb, g_, p_, mn_, mx_) do { \
    atomicMax(&s_stats[      (bb)], enc_f(g_));  \
    atomicMin(&s_stats[ 8  + (bb)], enc_f(p_));  \
    atomicMin(&s_stats[16  + (bb)], enc_f(mn_)); \
    atomicMax(&s_stats[24  + (bb)], enc_f(mx_)); } while (0)

__global__ __launch_bounds__(THREADS) void k_stats(
        const float* __restrict__ coord, const int* __restrict__ segment,
        const int* __restrict__ offset, unsigned* __restrict__ ws, int n, int nb) {
    __shared__ unsigned s_stats[32];
    const int tid = threadIdx.x;
    if (tid < 32) s_stats[tid] = ident_w(tid);
    if (blockIdx.x == 0 && tid == THREADS - 1) {       // no-k_init: zero acc + done here
        *(double*)(ws + 32) = 0.0;
        ws[34] = 0u;
    }
    int roff[8];
    #pragma unroll
    for (int j = 0; j < 8; ++j) roff[j] = (j < nb) ? offset[j] : 0x7FFFFFFF;
    __syncthreads();

    const int chunk = (n + (int)gridDim.x - 1) / (int)gridDim.x;
    const int start = blockIdx.x * chunk;
    const int end   = min(n, start + chunk);

    float lg = -INFINITY, lp = INFINITY, lmn = INFINITY, lmx = -INFINITY;

    if (start < end) {
        int ba = 0, bb = 0;
        #pragma unroll
        for (int j = 0; j < 8; ++j) { ba += (start >= roff[j]); bb += ((end - 1) >= roff[j]); }
        if (ba == bb) {
            // ---- fast path: whole chunk in one cloud; coalesced scalar loads, 8x MLP ----
            int i = start + tid;
            for (; i + (UNROLL - 1) * THREADS < end; i += UNROLL * THREADS) {
                float z[UNROLL]; int s[UNROLL];
                #pragma unroll
                for (int k = 0; k < UNROLL; ++k) z[k] = coord[3 * (i + k * THREADS) + 2];
                #pragma unroll
                for (int k = 0; k < UNROLL; ++k) s[k] = segment[i + k * THREADS];
                #pragma unroll
                for (int k = 0; k < UNROLL; ++k) {
                    lmn = fminf(lmn, z[k]);
                    lmx = fmaxf(lmx, z[k]);
                    lg  = fmaxf(lg, (s[k] == 0) ? z[k] : -INFINITY);
                    lp  = fminf(lp, (s[k] != 0) ? z[k] : INFINITY);
                }
            }
            for (; i < end; i += THREADS) {
                float z = coord[3 * i + 2]; int s = segment[i];
                lmn = fminf(lmn, z); lmx = fmaxf(lmx, z);
                lg  = fmaxf(lg, (s == 0) ? z : -INFINITY);
                lp  = fminf(lp, (s != 0) ? z : INFINITY);
            }
            #pragma unroll
            for (int m = 32; m; m >>= 1) {
                lg  = fmaxf(lg,  __shfl_xor(lg,  m, 64));
                lp  = fminf(lp,  __shfl_xor(lp,  m, 64));
                lmn = fminf(lmn, __shfl_xor(lmn, m, 64));
                lmx = fmaxf(lmx, __shfl_xor(lmx, m, 64));
            }
            if ((tid & 63) == 0) FLUSH_LDS(ba, lg, lp, lmn, lmx);
        } else {
            // ---- slow path (<= B-1 boundary blocks): per-point batch tracking ----
            int curb = -1;
            for (int i = start + tid; i < end; i += THREADS) {
                float z = coord[3 * i + 2]; int s = segment[i], b;
                CNT_B(i, b);
                if (b != curb) {
                    if (curb >= 0) FLUSH_LDS(curb, lg, lp, lmn, lmx);
                    lg = -INFINITY; lp = INFINITY; lmn = INFINITY; lmx = -INFINITY;
                    curb = b;
                }
                lmn = fminf(lmn, z); lmx = fmaxf(lmx, z);
                if (s == 0) lg = fmaxf(lg, z); else lp = fminf(lp, z);
            }
            if (curb >= 0) FLUSH_LDS(curb, lg, lp, lmn, lmx);
        }
    }
    __syncthreads();
    // every block (incl. empty) publishes its 32-word record with plain stores
    if (tid < 32) SLOT(ws, blockIdx.x)[tid] = s_stats[tid];
}

__device__ __forceinline__ float point_loss(float p0, float p1, int s, float z, float mu) {
    float m   = fmaxf(p0, p1);
    float lse = m + logf(expf(p0 - m) + expf(p1 - m));
    float lpt = ((s == 0) ? p0 : p1) - lse;
    float pt  = expf(lpt);
    float om  = 1.0f - pt;
    float loss = -lpt * om * om;           // LOSS_WEIGHT=ALPHA=1, GAMMA=2
    float d  = z - mu;
    float cf = (z <= mu) ? 50.0f : 3.125f; // 1/(2*0.1^2), 1/(2*0.4^2)
    float w  = expf(-d * d * cf);
    if (z > mu && d > 0.8f) w = 0.1f;      // d > 2*0.4 -> MIN_VAL
    return loss * w;
}

__global__ __launch_bounds__(THREADS) void k_loss(
        const float* __restrict__ pred, const float* __restrict__ coord,
        const int* __restrict__ segment, const int* __restrict__ offset,
        unsigned* __restrict__ ws, float* __restrict__ out, int n, int nb) {
    __shared__ unsigned s_comb[32];
    __shared__ float    s_mu[8];
    __shared__ float    s_part[THREADS / 64];
    const int tid = threadIdx.x;
    int roff[8];
    #pragma unroll
    for (int j = 0; j < 8; ++j) roff[j] = (j < nb) ? offset[j] : 0x7FFFFFFF;

    // ---- reduce the 256 per-block stat records (coalesced reads + LDS atomics) ----
    if (tid < 32) s_comb[tid] = ident_w(tid);
    __syncthreads();
    {
        const int w = tid & 31, g = tid >> 5;          // 32 groups x 32 words
        unsigned v = ident_w(w);
        #pragma unroll
        for (int j = 0; j < NBLOCKS / 32; ++j) {
            unsigned u = SLOT((const unsigned*)ws, g * (NBLOCKS / 32) + j)[w];
            v = (w < 8 || w >= 24) ? max(v, u) : min(v, u);
        }
        if (w < 8 || w >= 24) atomicMax(&s_comb[w], v);
        else                  atomicMin(&s_comb[w], v);
    }
    __syncthreads();
    if (tid < 8) {
        unsigned ug = s_comb[tid], up = s_comb[8 + tid];
        float g = dec_f(ug), p = dec_f(up);
        if (ug == ENC_NEG_INF) g = dec_f(s_comb[16 + tid]);  // no ground -> z.min
        if (up == ENC_POS_INF) p = dec_f(s_comb[24 + tid]);  // no plant  -> z.max
        s_mu[tid] = g + (p - g) * 0.5f;
    }
    __syncthreads();

    const int chunk = (n + (int)gridDim.x - 1) / (int)gridDim.x;
    const int start = blockIdx.x * chunk;
    const int end   = min(n, start + chunk);
    const float2* pred2 = (const float2*)pred;

    float lsum = 0.0f;
    if (start < end) {
        int ba = 0, bb = 0;
        #pragma unroll
        for (int j = 0; j < 8; ++j) { ba += (start >= roff[j]); bb += ((end - 1) >= roff[j]); }
        if (ba == bb) {
            const float mu = s_mu[ba];       // hoisted, no LDS in hot loop
            int i = start + tid;
            for (; i + (UNROLL - 1) * THREADS < end; i += UNROLL * THREADS) {
                float z[UNROLL]; int s[UNROLL]; float2 pp[UNROLL];
                #pragma unroll
                for (int k = 0; k < UNROLL; ++k) pp[k] = pred2[i + k * THREADS];
                #pragma unroll
                for (int k = 0; k < UNROLL; ++k) z[k] = coord[3 * (i + k * THREADS) + 2];
                #pragma unroll
                for (int k = 0; k < UNROLL; ++k) s[k] = segment[i + k * THREADS];
                #pragma unroll
                for (int k = 0; k < UNROLL; ++k)
                    lsum += point_loss(pp[k].x, pp[k].y, s[k], z[k], mu);
            }
            for (; i < end; i += THREADS) {
                float2 pp = pred2[i];
                lsum += point_loss(pp.x, pp.y, segment[i], coord[3 * i + 2], mu);
            }
        } else {
            for (int i = start + tid; i < end; i += THREADS) {
                int b; CNT_B(i, b);
                float2 pp = pred2[i];
                lsum += point_loss(pp.x, pp.y, segment[i], coord[3 * i + 2], s_mu[b]);
            }
        }
    }

    #pragma unroll
    for (int off = 32; off > 0; off >>= 1) lsum += __shfl_down(lsum, off, 64);
    if ((tid & 63) == 0) s_part[tid >> 6] = lsum;
    __syncthreads();
    if (tid == 0) {
        float t = 0.0f;
        #pragma unroll
        for (int wv = 0; wv < THREADS / 64; ++wv) t += s_part[wv];
        double* acc = (double*)(ws + 32);
        atomicAdd(acc, (double)t);
        __threadfence();
        unsigned c = atomicAdd(&ws[34], 1u);
        if (c == (unsigned)gridDim.x - 1u) {       // last block finalizes
            double v = atomicAdd(acc, 0.0);        // coherent read via atomic
            out[0] = (float)(v / (double)n);
        }
    }
}

extern "C" void kernel_launch(void* const* d_in, const int* in_sizes, int n_in,
                              void* d_out, int out_size, void* d_ws, size_t ws_size,
                              hipStream_t stream) {
    const float* pred    = (const float*)d_in[0];
    const float* coord   = (const float*)d_in[1];
    const int*   segment = (const int*)d_in[2];
    const int*   offset  = (const int*)d_in[3];
    const int n  = in_sizes[2];
    const int nb = in_sizes[3];

    unsigned* ws = (unsigned*)d_ws;

    hipLaunchKernelGGL(k_stats, dim3(NBLOCKS), dim3(THREADS), 0, stream,
                       coord, segment, offset, ws, n, nb);
    hipLaunchKernelGGL(k_loss,  dim3(NBLOCKS), dim3(THREADS), 0, stream,
                       pred, coord, segment, offset, ws, (float*)d_out, n, nb);
}